// Round 12
// baseline (980.142 us; speedup 1.0000x reference)
//
#include <hip/hip_runtime.h>
#include <hip/hip_bf16.h>
#include <stdint.h>

#define N_ATOMS 500000
#define N_MOLS  25000
#define HID     300
#define WS_ELE  102400    // elements per repacked W matrix (20*10*64*8)
#define NTILE   7813      // ceil(500000/64)

typedef __attribute__((ext_vector_type(8)))  short          short8v;
typedef __attribute__((ext_vector_type(16))) float          f32x16;

static __device__ __forceinline__ unsigned short f2bf(float f) {
  unsigned int u = __float_as_uint(f);
  u += 0x7fffu + ((u >> 16) & 1u);   // round-to-nearest-even
  return (unsigned short)(u >> 16);
}

// compiler lowers scalar casts to v_cvt_pk_bf16_f32
static __device__ __forceinline__ short8v pack8(float4 a, float4 b) {
  union { __hip_bfloat16 h[8]; short8v v; } u;
  u.h[0] = __float2bfloat16(a.x); u.h[1] = __float2bfloat16(a.y);
  u.h[2] = __float2bfloat16(a.z); u.h[3] = __float2bfloat16(a.w);
  u.h[4] = __float2bfloat16(b.x); u.h[5] = __float2bfloat16(b.y);
  u.h[6] = __float2bfloat16(b.z); u.h[7] = __float2bfloat16(b.w);
  return u.v;
}

// async global->LDS, 16B per lane; lds base wave-uniform.
static __device__ __forceinline__ void stage16(const char* gsrc, char* ldst, int ln) {
  __builtin_amdgcn_global_load_lds(
      (const __attribute__((address_space(1))) void*)(gsrc + ln * 16),
      (__attribute__((address_space(3))) void*)ldst, 16, 0, 0);
}

// ---------------------------------------------------------------------------
// Prep: repack W1/V1 into B-fragment order [kc16:20][nt:10][lane:64][j:8];
// pad biases/readout vectors to 320; zero segment sums and outA/outW
// (fused_ffn accumulates into them via atomics).
// ---------------------------------------------------------------------------
__global__ void prep_kernel(
    const float* __restrict__ W1, const float* __restrict__ V1,
    const float* __restrict__ b1, const float* __restrict__ vb1,
    const float* __restrict__ W2, const float* __restrict__ V2,
    unsigned short* __restrict__ W1s, unsigned short* __restrict__ V1s,
    float* __restrict__ b1p, float* __restrict__ vb1p,
    float* __restrict__ W2p, float* __restrict__ V2p,
    float* __restrict__ sums, float* __restrict__ outAW)
{
  const int t = blockIdx.x * 256 + threadIdx.x;
  if (t < 2 * WS_ELE) {
    const float* src = (t < WS_ELE) ? W1 : V1;
    unsigned short* dst = (t < WS_ELE) ? W1s : V1s;
    const int i    = (t < WS_ELE) ? t : t - WS_ELE;
    const int j    = i & 7;
    const int lane = (i >> 3) & 63;
    const int nt   = (i >> 9) % 10;
    const int kc16 = i / 5120;
    const int k = kc16 * 16 + (lane >> 5) * 8 + j;
    const int n = nt * 32 + (lane & 31);
    const float v = (k < HID && n < HID) ? src[k * HID + n] : 0.f;
    dst[i] = f2bf(v);
  } else if (t < 2 * WS_ELE + 1280) {
    const int i = t - 2 * WS_ELE;
    const int which = i / 320;
    const int e = i - which * 320;
    const float* s = (which == 0) ? b1 : (which == 1) ? vb1 : (which == 2) ? W2 : V2;
    float*       d = (which == 0) ? b1p : (which == 1) ? vb1p : (which == 2) ? W2p : V2p;
    d[e] = (e < HID) ? s[e] : 0.f;
  } else if (t < 2 * WS_ELE + 1280 + 2 * N_MOLS) {
    sums[t - (2 * WS_ELE + 1280)] = 0.f;
  } else if (t < 2 * WS_ELE + 1280 + 2 * N_MOLS + 2 * N_ATOMS) {
    outAW[t - (2 * WS_ELE + 1280 + 2 * N_MOLS)] = 0.f;
  }
}

// ---------------------------------------------------------------------------
// Fused FFN x2, B-RESIDENT / ZERO-STEADY-STATE-BARRIER design.
// Grid = 256 blocks (1/CU), 512 thr = 8 waves. Block is pinned to ONE
// (mtx,ch) quarter of B: 95KB = [kc16:19][nt:5] frags, loaded into LDS ONCE
// via global_load_lds, then ONE __syncthreads -- after that, waves are fully
// independent (no barriers, no coupling): each wave grid-strides over
// 64-atom tiles (stride 512 streams over 7813 tiles), A streamed HBM->regs
// with depth-1 chunk prefetch (MFMA cover 1520cy >> HBM 900cy), B via
// conflict-free ds_read_b128 from the resident quarter. acc[2][5] = 160
// AGPR; ~235 regs/wave < 256 cap at 8 waves/CU. Per-wave partial (64 atoms
// x 160 cols) is shfl-reduced and atomically added to outA/outW (2
// commutative f32 adds per atom per matrix -> deterministic).
// ---------------------------------------------------------------------------
__global__ __launch_bounds__(512, 1) void fused_ffn(
    const float* __restrict__ hidden,
    const unsigned short* __restrict__ W1s, const unsigned short* __restrict__ V1s,
    const float* __restrict__ b1p, const float* __restrict__ vb1p,
    const float* __restrict__ W2p, const float* __restrict__ V2p,
    const float* __restrict__ b2, const float* __restrict__ vb2,
    float* __restrict__ outA, float* __restrict__ outW)
{
  __shared__ char ldsB[95 * 1024];   // 97,280 B: one (mtx,ch) quarter of B

  const int tid = (int)threadIdx.x;
  const int ln  = tid & 63;
  const int wv  = tid >> 6;          // 0..7
  const int q   = blockIdx.x & 3;
  const int mtx = q & 1;             // 0 = W-pass, 1 = V-pass
  const int ch  = q >> 1;            // col half (160 of 320 cols)
  const int l31 = ln & 31;
  const int lh  = ln >> 5;

  // ---- one-time B quarter load: 95 x 1KB pieces over 8 waves ----
  {
    const char* srcM = mtx ? (const char*)V1s : (const char*)W1s;
    #pragma unroll
    for (int r = 0; r < 12; ++r) {
      const int p = wv * 12 + r;
      if (p < 95) {
        const int kc16 = p / 5;
        const int nt   = p - kc16 * 5;
        stage16(srcM + kc16 * 10240 + (ch * 5 + nt) * 1024, ldsB + p * 1024, ln);
      }
    }
  }

  // per-wave constants
  float bv[5], w2[5];
  {
    const float* bbv = mtx ? vb1p : b1p;
    const float* ww2 = mtx ? V2p  : W2p;
    #pragma unroll
    for (int nt = 0; nt < 5; ++nt) {
      const int cix = ch * 160 + nt * 32 + l31;
      bv[nt] = bbv[cix];
      w2[nt] = ww2[cix];
    }
  }
  const float biasadd = (ch == 0) ? (mtx ? vb2[0] : b2[0]) : 0.f;
  float* const outP = mtx ? outW : outA;

  __syncthreads();   // B resident (drains the global_load_lds). LAST barrier.

  // ---- independent per-wave tile stream ----
  const char* const hbase = (const char*)hidden;

  #pragma unroll 1
  for (int tile = (blockIdx.x >> 2) * 8 + wv; tile < NTILE; tile += 512) {
    const long a0 = (long)tile * 64;
    long r0 = a0 + l31;       if (r0 > N_ATOMS - 1) r0 = N_ATOMS - 1;
    long r1 = a0 + 32 + l31;  if (r1 > N_ATOMS - 1) r1 = N_ATOMS - 1;
    const char* hp0 = hbase + r0 * 1200 + lh * 32;
    const char* hp1 = hbase + r1 * 1200 + lh * 32;

    f32x16 acc[2][5] = {};

    // depth-1 A prefetch across 19 K=16 chunks (fully unrolled: SSA regs)
    float4 c00 = *reinterpret_cast<const float4*>(hp0);
    float4 c01 = *reinterpret_cast<const float4*>(hp0 + 16);
    float4 c10 = *reinterpret_cast<const float4*>(hp1);
    float4 c11 = *reinterpret_cast<const float4*>(hp1 + 16);
    // NOTE: chunk 18 reads bytes [1152,1216) of the 1200-B row: the last 16B
    // spill into the next row but multiply B's k>=300 zero-pad -> harmless.
    #pragma unroll
    for (int c = 0; c < 19; ++c) {
      float4 n00, n01, n10, n11;
      if (c < 18) {
        n00 = *reinterpret_cast<const float4*>(hp0 + (c + 1) * 64);
        n01 = *reinterpret_cast<const float4*>(hp0 + (c + 1) * 64 + 16);
        n10 = *reinterpret_cast<const float4*>(hp1 + (c + 1) * 64);
        n11 = *reinterpret_cast<const float4*>(hp1 + (c + 1) * 64 + 16);
      }
      const short8v a0f = pack8(c00, c01);
      const short8v a1f = pack8(c10, c11);
      #pragma unroll
      for (int nt = 0; nt < 5; ++nt) {
        const short8v bf = *reinterpret_cast<const short8v*>(
            ldsB + (c * 5 + nt) * 1024 + ln * 16);
        acc[0][nt] = __builtin_amdgcn_mfma_f32_32x32x16_bf16(a0f, bf, acc[0][nt], 0, 0, 0);
        acc[1][nt] = __builtin_amdgcn_mfma_f32_32x32x16_bf16(a1f, bf, acc[1][nt], 0, 0, 0);
      }
      if (c < 18) { c00 = n00; c01 = n01; c10 = n10; c11 = n11; }
    }

    // ---- epilogue: relu -> dot(W2) -> 32-lane col reduce -> atomicAdd ----
    #pragma unroll
    for (int rb = 0; rb < 2; ++rb) {
      #pragma unroll
      for (int r = 0; r < 16; ++r) {
        float s = 0.f;
        #pragma unroll
        for (int nt = 0; nt < 5; ++nt) {
          const float x = fmaxf(acc[rb][nt][r] + bv[nt], 0.f);
          s = fmaf(x, w2[nt], s);
        }
        s += __shfl_xor(s, 1);
        s += __shfl_xor(s, 2);
        s += __shfl_xor(s, 4);
        s += __shfl_xor(s, 8);
        s += __shfl_xor(s, 16);
        if (l31 == 0) {
          const long atom = a0 + rb * 32 + (r & 3) + 8 * (r >> 2) + 4 * lh;
          if (atom < N_ATOMS) atomicAdd(&outP[atom], s + biasadd);
        }
      }
    }
  }
}

// ---------------------------------------------------------------------------
// Segment sums: sorted seg_ids, run-compress 8 atoms/thread before atomics.
// ---------------------------------------------------------------------------
__global__ void segsum_kernel(
    const float* __restrict__ outA, const float* __restrict__ outW,
    const int* __restrict__ seg,
    float* __restrict__ sum_o, float* __restrict__ sum_w)
{
  const long i0 = ((long)blockIdx.x * 256 + threadIdx.x) * 8;
  if (i0 >= N_ATOMS) return;
  const int4   s0 = *reinterpret_cast<const int4*>(seg + i0);
  const int4   s1 = *reinterpret_cast<const int4*>(seg + i0 + 4);
  const float4 o0 = *reinterpret_cast<const float4*>(outA + i0);
  const float4 o1 = *reinterpret_cast<const float4*>(outA + i0 + 4);
  const float4 w0 = *reinterpret_cast<const float4*>(outW + i0);
  const float4 w1 = *reinterpret_cast<const float4*>(outW + i0 + 4);
  const int   ss[8] = {s0.x, s0.y, s0.z, s0.w, s1.x, s1.y, s1.z, s1.w};
  const float oo[8] = {o0.x, o0.y, o0.z, o0.w, o1.x, o1.y, o1.z, o1.w};
  const float ww[8] = {w0.x, w0.y, w0.z, w0.w, w1.x, w1.y, w1.z, w1.w};
  int cur = ss[0];
  float ao = 0.f, aw = 0.f;
  #pragma unroll
  for (int j = 0; j < 8; ++j) {
    if (ss[j] != cur) {
      atomicAdd(&sum_o[cur], ao);
      atomicAdd(&sum_w[cur], aw);
      cur = ss[j]; ao = 0.f; aw = 0.f;
    }
    ao += oo[j]; aw += ww[j];
  }
  atomicAdd(&sum_o[cur], ao);
  atomicAdd(&sum_w[cur], aw);
}

// ---------------------------------------------------------------------------
// Final: out = output + weights * (0 - sum_o[seg]) / sum_w'[seg]
// ---------------------------------------------------------------------------
__global__ void final_kernel(
    const float* __restrict__ outA, const float* __restrict__ outW,
    const int* __restrict__ seg,
    const float* __restrict__ sum_o, const float* __restrict__ sum_w,
    float* __restrict__ out)
{
  const long i0 = ((long)blockIdx.x * 256 + threadIdx.x) * 4;
  if (i0 >= N_ATOMS) return;
  const int4   s4 = *reinterpret_cast<const int4*>(seg + i0);
  const float4 o4 = *reinterpret_cast<const float4*>(outA + i0);
  const float4 w4 = *reinterpret_cast<const float4*>(outW + i0);
  const int   ss[4] = {s4.x, s4.y, s4.z, s4.w};
  const float oo[4] = {o4.x, o4.y, o4.z, o4.w};
  const float ww[4] = {w4.x, w4.y, w4.z, w4.w};
  float r[4];
  #pragma unroll
  for (int j = 0; j < 4; ++j) {
    const int s = ss[j];
    float sw = sum_w[s];
    sw = (sw == 0.f) ? 1.f : sw;
    const float corr = (0.f - sum_o[s]) / sw;
    r[j] = oo[j] + ww[j] * corr;
  }
  *reinterpret_cast<float4*>(out + i0) = make_float4(r[0], r[1], r[2], r[3]);
}

// ---------------------------------------------------------------------------
extern "C" void kernel_launch(void* const* d_in, const int* in_sizes, int n_in,
                              void* d_out, int out_size, void* d_ws, size_t ws_size,
                              hipStream_t stream)
{
  const float* hidden = (const float*)d_in[0];
  const int*   seg    = (const int*)d_in[1];
  const float* W1     = (const float*)d_in[2];
  const float* b1     = (const float*)d_in[3];
  const float* W2     = (const float*)d_in[4];
  const float* b2     = (const float*)d_in[5];
  const float* V1     = (const float*)d_in[6];
  const float* vb1    = (const float*)d_in[7];
  const float* V2     = (const float*)d_in[8];
  const float* vb2    = (const float*)d_in[9];

  char* ws = (char*)d_ws;
  float*          outA  = (float*)(ws + 0);                 // 2,000,000 B
  float*          outW  = (float*)(ws + 2000000);           // 2,000,000 B
  float*          sum_o = (float*)(ws + 4000000);           //   100,000 B
  float*          sum_w = (float*)(ws + 4100000);           //   100,000 B
  unsigned short* W1s   = (unsigned short*)(ws + 4200000);  //   204,800 B
  unsigned short* V1s   = (unsigned short*)(ws + 4404800);  //   204,800 B
  float*          b1p   = (float*)(ws + 4609600);           //     1,280 B
  float*          vb1p  = (float*)(ws + 4610880);
  float*          W2p   = (float*)(ws + 4612160);
  float*          V2p   = (float*)(ws + 4613440);

  // prep covers repack + biases + sum zero + outA/outW zero
  const int prep_threads = 2 * WS_ELE + 1280 + 2 * N_MOLS + 2 * N_ATOMS;
  prep_kernel<<<(prep_threads + 255) / 256, 256, 0, stream>>>(
      W1, V1, b1, vb1, W2, V2,
      W1s, V1s, b1p, vb1p, W2p, V2p, sum_o, outA);

  fused_ffn<<<256, 512, 0, stream>>>(hidden, W1s, V1s, b1p, vb1p, W2p, V2p,
                                     b2, vb2, outA, outW);

  segsum_kernel<<<(N_ATOMS / 8 + 255) / 256, 256, 0, stream>>>(outA, outW, seg,
                                                               sum_o, sum_w);

  final_kernel<<<(N_ATOMS / 4 + 255) / 256, 256, 0, stream>>>(outA, outW, seg,
                                                              sum_o, sum_w,
                                                              (float*)d_out);
}

// Round 13
// 505.260 us; speedup vs baseline: 1.9399x; 1.9399x over previous
//
#include <hip/hip_runtime.h>
#include <hip/hip_bf16.h>
#include <stdint.h>

#define N_ATOMS 500000
#define N_MOLS  25000
#define HID     300
#define BA      64        // atoms per block
#define WS_ELE  102400    // elements per repacked W matrix (20*10*64*8)
#define AROWB   616       // A row stride in LDS bytes (308 bf16; ~2-way banks)

typedef __attribute__((ext_vector_type(8)))  short          short8v;
typedef __attribute__((ext_vector_type(16))) float          f32x16;

static __device__ __forceinline__ unsigned short f2bf(float f) {
  unsigned int u = __float_as_uint(f);
  u += 0x7fffu + ((u >> 16) & 1u);   // round-to-nearest-even
  return (unsigned short)(u >> 16);
}

// ---------------------------------------------------------------------------
// Prep: repack W1/V1 into B-fragment order [kc16:20][nt:10][lane:64][j:8]
// (k = kc16*16 + (lane>>5)*8 + j, n = nt*32 + (lane&31)), pad biases/readout
// vectors to 320, zero the segment-sum accumulators.
// ---------------------------------------------------------------------------
__global__ void prep_kernel(
    const float* __restrict__ W1, const float* __restrict__ V1,
    const float* __restrict__ b1, const float* __restrict__ vb1,
    const float* __restrict__ W2, const float* __restrict__ V2,
    unsigned short* __restrict__ W1s, unsigned short* __restrict__ V1s,
    float* __restrict__ b1p, float* __restrict__ vb1p,
    float* __restrict__ W2p, float* __restrict__ V2p,
    float* __restrict__ sums)
{
  const int t = blockIdx.x * 256 + threadIdx.x;
  if (t < 2 * WS_ELE) {
    const float* src = (t < WS_ELE) ? W1 : V1;
    unsigned short* dst = (t < WS_ELE) ? W1s : V1s;
    const int i    = (t < WS_ELE) ? t : t - WS_ELE;
    const int j    = i & 7;
    const int lane = (i >> 3) & 63;
    const int nt   = (i >> 9) % 10;
    const int kc16 = i / 5120;
    const int k = kc16 * 16 + (lane >> 5) * 8 + j;
    const int n = nt * 32 + (lane & 31);
    const float v = (k < HID && n < HID) ? src[k * HID + n] : 0.f;
    dst[i] = f2bf(v);
  } else if (t < 2 * WS_ELE + 1280) {
    const int i = t - 2 * WS_ELE;
    const int which = i / 320;
    const int e = i - which * 320;
    const float* s = (which == 0) ? b1 : (which == 1) ? vb1 : (which == 2) ? W2 : V2;
    float*       d = (which == 0) ? b1p : (which == 1) ? vb1p : (which == 2) ? W2p : V2p;
    d[e] = (e < HID) ? s[e] : 0.f;
  } else if (t < 2 * WS_ELE + 1280 + 2 * N_MOLS) {
    sums[t - (2 * WS_ELE + 1280)] = 0.f;
  }
}

// ---------------------------------------------------------------------------
// Fused FFN x2: A-once (r7 traffic) x deep-pipeline (r11 engine).
// Block = 64 atoms, 4 waves = {mtx:2} x {ch:2}; wave = 64 atoms x 160 cols of
// ONE matrix, acc[2][5] f32x16 = 160 AGPR. A staged ONCE per block into LDS
// bf16 row-major (spill-free 2-batch pattern), ONE __syncthreads, then a
// FULLY-UNROLLED 19-chunk K-loop with NO barriers: B streamed from L2 into a
// 3-buffer rotating register pipeline (10 x 1KB loads always in flight,
// use-distance = 3 chunks >> L2 latency; compiler emits counted vmcnt).
// A via ds_read_b128. 2 blocks/CU (launch_bounds 256-reg cap).
// ---------------------------------------------------------------------------
__global__ __launch_bounds__(256, 2) void fused_ffn(
    const float* __restrict__ hidden,
    const unsigned short* __restrict__ W1s, const unsigned short* __restrict__ V1s,
    const float* __restrict__ b1p, const float* __restrict__ vb1p,
    const float* __restrict__ W2p, const float* __restrict__ V2p,
    const float* __restrict__ b2, const float* __restrict__ vb2,
    float* __restrict__ outA, float* __restrict__ outW)
{
  __shared__ char ldsA[BA * AROWB];   // 39,424 B
  __shared__ float sOutA[BA];
  __shared__ float sOutW[BA];

  const int tid = (int)threadIdx.x;
  const int ln  = tid & 63;
  const int wv  = tid >> 6;
  const int mtx = wv & 1;          // 0 = W-pass, 1 = V-pass
  const int ch  = wv >> 1;         // col half (160 cols)
  const int l31 = ln & 31;
  const int lh  = ln >> 5;
  const long base = (long)blockIdx.x * BA;

  // wave's B stream: 160 cols of one matrix, frag-ordered, 5KB per K=16 chunk
  const char* bwave = (mtx ? (const char*)V1s : (const char*)W1s) + ch * 5120;

  // ---- prologue: issue B(0..2) into the 3 rotating buffers FIRST ----
  short8v b0[5], b1v[5], b2v[5];
  #pragma unroll
  for (int nt = 0; nt < 5; ++nt)
    b0[nt] = *reinterpret_cast<const short8v*>(bwave + nt * 1024 + ln * 16);
  #pragma unroll
  for (int nt = 0; nt < 5; ++nt)
    b1v[nt] = *reinterpret_cast<const short8v*>(bwave + 10240 + nt * 1024 + ln * 16);
  #pragma unroll
  for (int nt = 0; nt < 5; ++nt)
    b2v[nt] = *reinterpret_cast<const short8v*>(bwave + 20480 + nt * 1024 + ln * 16);

  // ---- A: stage 64 rows x 300 f32 -> bf16 LDS, row-major, 2 batches ----
  // slots: i = tid + j*256, row = i/76, c4 = i%76 (c4==75 -> zero pad)
  #pragma unroll
  for (int bt = 0; bt < 2; ++bt) {
    const int nb = bt ? 9 : 10;
    float4 tmp[10];
    #pragma unroll
    for (int m = 0; m < 10; ++m) {
      if (m >= nb) break;
      const int i   = tid + (bt * 10 + m) * 256;
      const int row = i / 76;
      const int c4  = i - row * 76;
      float4 v = make_float4(0.f, 0.f, 0.f, 0.f);
      const long atom = base + row;
      if (c4 < 75 && atom < N_ATOMS)
        v = *reinterpret_cast<const float4*>(hidden + atom * (long)HID + c4 * 4);
      tmp[m] = v;
    }
    #pragma unroll
    for (int m = 0; m < 10; ++m) {
      if (m >= nb) break;
      const int i   = tid + (bt * 10 + m) * 256;
      const int row = i / 76;
      const int c4  = i - row * 76;
      ushort4 b;
      b.x = (unsigned short)__bfloat16_as_ushort(__float2bfloat16(tmp[m].x));
      b.y = (unsigned short)__bfloat16_as_ushort(__float2bfloat16(tmp[m].y));
      b.z = (unsigned short)__bfloat16_as_ushort(__float2bfloat16(tmp[m].z));
      b.w = (unsigned short)__bfloat16_as_ushort(__float2bfloat16(tmp[m].w));
      *reinterpret_cast<ushort4*>(ldsA + row * AROWB + c4 * 8) = b;
    }
  }
  __syncthreads();   // A resident; B(0..2) retired by the drain. LAST barrier.

  const char* aB0 = ldsA + l31 * AROWB + lh * 16;
  const char* aB1 = aB0 + 32 * AROWB;

  f32x16 acc[2][5] = {};

  // CHUNK(c, BUF): MFMA chunk c from BUF, then refill BUF with B(c+3).
#define CHUNK(c, BUF)                                                          \
  do {                                                                         \
    const short8v a0_ = *reinterpret_cast<const short8v*>(aB0 + (c) * 32);     \
    const short8v a1_ = *reinterpret_cast<const short8v*>(aB1 + (c) * 32);     \
    _Pragma("unroll")                                                          \
    for (int nt_ = 0; nt_ < 5; ++nt_) {                                        \
      acc[0][nt_] = __builtin_amdgcn_mfma_f32_32x32x16_bf16(a0_, BUF[nt_],     \
                                                            acc[0][nt_], 0, 0, 0); \
      acc[1][nt_] = __builtin_amdgcn_mfma_f32_32x32x16_bf16(a1_, BUF[nt_],     \
                                                            acc[1][nt_], 0, 0, 0); \
    }                                                                          \
    if ((c) + 3 < 19) {                                                        \
      const char* s_ = bwave + ((c) + 3) * 10240;                              \
      _Pragma("unroll")                                                        \
      for (int nt_ = 0; nt_ < 5; ++nt_)                                        \
        BUF[nt_] = *reinterpret_cast<const short8v*>(s_ + nt_ * 1024 + ln * 16); \
    }                                                                          \
  } while (0)

  CHUNK(0,  b0);  CHUNK(1,  b1v); CHUNK(2,  b2v);
  CHUNK(3,  b0);  CHUNK(4,  b1v); CHUNK(5,  b2v);
  CHUNK(6,  b0);  CHUNK(7,  b1v); CHUNK(8,  b2v);
  CHUNK(9,  b0);  CHUNK(10, b1v); CHUNK(11, b2v);
  CHUNK(12, b0);  CHUNK(13, b1v); CHUNK(14, b2v);
  CHUNK(15, b0);  CHUNK(16, b1v); CHUNK(17, b2v);
  CHUNK(18, b0);
#undef CHUNK

  // ---- epilogue: out[atom] = sum_n relu(X+b1)*W2 + b2 ----
  float bv[5], w2[5];
  const float* bbv = mtx ? vb1p : b1p;
  const float* ww2 = mtx ? V2p  : W2p;
  #pragma unroll
  for (int nt = 0; nt < 5; ++nt) {
    const int cix = ch * 160 + nt * 32 + l31;
    bv[nt] = bbv[cix];
    w2[nt] = ww2[cix];
  }
  if (tid < BA) { sOutA[tid] = 0.f; sOutW[tid] = 0.f; }
  __syncthreads();

  float* sOut = mtx ? sOutW : sOutA;
  #pragma unroll
  for (int rb = 0; rb < 2; ++rb) {
    #pragma unroll
    for (int r = 0; r < 16; ++r) {
      float s = 0.f;
      #pragma unroll
      for (int nt = 0; nt < 5; ++nt) {
        const float x = fmaxf(acc[rb][nt][r] + bv[nt], 0.f);
        s = fmaf(x, w2[nt], s);
      }
      s += __shfl_xor(s, 1);
      s += __shfl_xor(s, 2);
      s += __shfl_xor(s, 4);
      s += __shfl_xor(s, 8);
      s += __shfl_xor(s, 16);
      if (l31 == 0) {
        const int row = rb * 32 + (r & 3) + 8 * (r >> 2) + 4 * lh;
        atomicAdd(&sOut[row], s);
      }
    }
  }
  __syncthreads();
  if (tid < BA) {
    const long atom = base + tid;
    if (atom < N_ATOMS) {
      outA[atom] = sOutA[tid] + b2[0];
      outW[atom] = sOutW[tid] + vb2[0];
    }
  }
}

// ---------------------------------------------------------------------------
// Segment sums: sorted seg_ids, run-compress 8 atoms/thread before atomics.
// ---------------------------------------------------------------------------
__global__ void segsum_kernel(
    const float* __restrict__ outA, const float* __restrict__ outW,
    const int* __restrict__ seg,
    float* __restrict__ sum_o, float* __restrict__ sum_w)
{
  const long i0 = ((long)blockIdx.x * 256 + threadIdx.x) * 8;
  if (i0 >= N_ATOMS) return;
  const int4   s0 = *reinterpret_cast<const int4*>(seg + i0);
  const int4   s1 = *reinterpret_cast<const int4*>(seg + i0 + 4);
  const float4 o0 = *reinterpret_cast<const float4*>(outA + i0);
  const float4 o1 = *reinterpret_cast<const float4*>(outA + i0 + 4);
  const float4 w0 = *reinterpret_cast<const float4*>(outW + i0);
  const float4 w1 = *reinterpret_cast<const float4*>(outW + i0 + 4);
  const int   ss[8] = {s0.x, s0.y, s0.z, s0.w, s1.x, s1.y, s1.z, s1.w};
  const float oo[8] = {o0.x, o0.y, o0.z, o0.w, o1.x, o1.y, o1.z, o1.w};
  const float ww[8] = {w0.x, w0.y, w0.z, w0.w, w1.x, w1.y, w1.z, w1.w};
  int cur = ss[0];
  float ao = 0.f, aw = 0.f;
  #pragma unroll
  for (int j = 0; j < 8; ++j) {
    if (ss[j] != cur) {
      atomicAdd(&sum_o[cur], ao);
      atomicAdd(&sum_w[cur], aw);
      cur = ss[j]; ao = 0.f; aw = 0.f;
    }
    ao += oo[j]; aw += ww[j];
  }
  atomicAdd(&sum_o[cur], ao);
  atomicAdd(&sum_w[cur], aw);
}

// ---------------------------------------------------------------------------
// Final: out = output + weights * (0 - sum_o[seg]) / sum_w'[seg]
// ---------------------------------------------------------------------------
__global__ void final_kernel(
    const float* __restrict__ outA, const float* __restrict__ outW,
    const int* __restrict__ seg,
    const float* __restrict__ sum_o, const float* __restrict__ sum_w,
    float* __restrict__ out)
{
  const long i0 = ((long)blockIdx.x * 256 + threadIdx.x) * 4;
  if (i0 >= N_ATOMS) return;
  const int4   s4 = *reinterpret_cast<const int4*>(seg + i0);
  const float4 o4 = *reinterpret_cast<const float4*>(outA + i0);
  const float4 w4 = *reinterpret_cast<const float4*>(outW + i0);
  const int   ss[4] = {s4.x, s4.y, s4.z, s4.w};
  const float oo[4] = {o4.x, o4.y, o4.z, o4.w};
  const float ww[4] = {w4.x, w4.y, w4.z, w4.w};
  float r[4];
  #pragma unroll
  for (int j = 0; j < 4; ++j) {
    const int s = ss[j];
    float sw = sum_w[s];
    sw = (sw == 0.f) ? 1.f : sw;
    const float corr = (0.f - sum_o[s]) / sw;
    r[j] = oo[j] + ww[j] * corr;
  }
  *reinterpret_cast<float4*>(out + i0) = make_float4(r[0], r[1], r[2], r[3]);
}

// ---------------------------------------------------------------------------
extern "C" void kernel_launch(void* const* d_in, const int* in_sizes, int n_in,
                              void* d_out, int out_size, void* d_ws, size_t ws_size,
                              hipStream_t stream)
{
  const float* hidden = (const float*)d_in[0];
  const int*   seg    = (const int*)d_in[1];
  const float* W1     = (const float*)d_in[2];
  const float* b1     = (const float*)d_in[3];
  const float* W2     = (const float*)d_in[4];
  const float* b2     = (const float*)d_in[5];
  const float* V1     = (const float*)d_in[6];
  const float* vb1    = (const float*)d_in[7];
  const float* V2     = (const float*)d_in[8];
  const float* vb2    = (const float*)d_in[9];

  char* ws = (char*)d_ws;
  float*          outA  = (float*)(ws + 0);          // 2,000,000 B
  float*          outW  = (float*)(ws + 2000000);    // 2,000,000 B
  float*          sum_o = (float*)(ws + 4000000);    //   100,000 B
  float*          sum_w = (float*)(ws + 4100000);    //   100,000 B
  unsigned short* W1s   = (unsigned short*)(ws + 4200000);  // 204,800 B
  unsigned short* V1s   = (unsigned short*)(ws + 4404800);  // 204,800 B
  float*          b1p   = (float*)(ws + 4609600);    // 1,280 B
  float*          vb1p  = (float*)(ws + 4610880);
  float*          W2p   = (float*)(ws + 4612160);
  float*          V2p   = (float*)(ws + 4613440);

  prep_kernel<<<1001, 256, 0, stream>>>(W1, V1, b1, vb1, W2, V2,
                                        W1s, V1s, b1p, vb1p, W2p, V2p, sum_o);

  const int nblk = (N_ATOMS + BA - 1) / BA;   // 7813
  fused_ffn<<<nblk, 256, 0, stream>>>(hidden, W1s, V1s, b1p, vb1p, W2p, V2p,
                                      b2, vb2, outA, outW);

  segsum_kernel<<<(N_ATOMS / 8 + 255) / 256, 256, 0, stream>>>(outA, outW, seg,
                                                               sum_o, sum_w);

  final_kernel<<<(N_ATOMS / 4 + 255) / 256, 256, 0, stream>>>(outA, outW, seg,
                                                              sum_o, sum_w,
                                                              (float*)d_out);
}